// Round 4
// baseline (333.044 us; speedup 1.0000x reference)
//
#include <hip/hip_runtime.h>
#include <hip/hip_fp16.h>

#define B_ 16
#define XL_ 1024
#define KL_ 512
#define D_ 1024
#define NEGC (-10000000.0f)

typedef _Float16 f16x8 __attribute__((ext_vector_type(8)));
typedef float f32x4 __attribute__((ext_vector_type(4)));
typedef unsigned short u16x8 __attribute__((ext_vector_type(8)));
typedef unsigned short u16x4 __attribute__((ext_vector_type(4)));

__device__ __forceinline__ unsigned short f2h(float f) {
  __half h = __float2half(f);
  return __half_as_ushort(h);
}

// ---------- prep: x_logits = x . w_input (wave per row) ----------
__global__ __launch_bounds__(256) void k_prep_x(const float* __restrict__ x,
    const float* __restrict__ w_input, float* __restrict__ xlog) {
  int wv = threadIdx.x >> 6, lane = threadIdx.x & 63;
  int row = blockIdx.x * 4 + wv;
  const float* src = x + (size_t)row * D_;
  float acc = 0.f;
#pragma unroll
  for (int j = 0; j < 4; ++j) {
    int d = j * 256 + lane * 4;
    float4 v = *(const float4*)(src + d);
    float4 w = *(const float4*)(w_input + d);
    acc += v.x * w.x + v.y * w.y + v.z * w.z + v.w * w.w;
  }
#pragma unroll
  for (int sh = 32; sh >= 1; sh >>= 1) acc += __shfl_xor(acc, sh);
  if (lane == 0) xlog[row] = acc;
}

// ---------- prep: key -> fp16 Kh, key_logits = key . w_key ----------
__global__ __launch_bounds__(256) void k_prep_key(const float* __restrict__ key,
    const float* __restrict__ w_key, unsigned short* __restrict__ Kh,
    float* __restrict__ klog) {
  int wv = threadIdx.x >> 6, lane = threadIdx.x & 63;
  int row = blockIdx.x * 4 + wv;
  const float* src = key + (size_t)row * D_;
  unsigned short* dst = Kh + (size_t)row * D_;
  float acc = 0.f;
#pragma unroll
  for (int j = 0; j < 4; ++j) {
    int d = j * 256 + lane * 4;
    float4 v = *(const float4*)(src + d);
    float4 w = *(const float4*)(w_key + d);
    acc += v.x * w.x + v.y * w.y + v.z * w.z + v.w * w.w;
    u16x4 hv;
    hv[0] = f2h(v.x); hv[1] = f2h(v.y); hv[2] = f2h(v.z); hv[3] = f2h(v.w);
    *(u16x4*)(dst + d) = hv;
  }
#pragma unroll
  for (int sh = 32; sh >= 1; sh >>= 1) acc += __shfl_xor(acc, sh);
  if (lane == 0) klog[row] = acc;
}

// ---------- transpose Kh [b][k][d] -> KhT [b][d][k] (64x64 tiles) ----------
__global__ __launch_bounds__(256) void k_transpose(const unsigned short* __restrict__ Kh,
    unsigned short* __restrict__ KhT) {
  __shared__ unsigned short tile[64][72];
  int bid = blockIdx.x;
  int b = bid >> 7; int rem = bid & 127; int kt = rem >> 4; int dt = rem & 15;
  const unsigned short* src = Kh + ((size_t)b * KL_ + kt * 64) * D_ + dt * 64;
  int tr = threadIdx.x >> 3, tc = (threadIdx.x & 7) * 8;
#pragma unroll
  for (int i = 0; i < 2; ++i) {
    int r = i * 32 + tr;
    u16x8 v = *(const u16x8*)(src + (size_t)r * D_ + tc);
    *(u16x8*)(&tile[r][tc]) = v;
  }
  __syncthreads();
  unsigned short* dst = KhT + ((size_t)b * D_ + dt * 64) * KL_ + kt * 64;
#pragma unroll
  for (int i = 0; i < 2; ++i) {
    int dr = i * 32 + tr;
    u16x8 v;
#pragma unroll
    for (int j = 0; j < 8; ++j) v[j] = tile[tc + j][dr];
    *(u16x8*)(dst + (size_t)dr * KL_ + tc) = v;
  }
}

// ---------- main attention kernel ----------
// 512 thr (8 waves), 16 x-rows x KL=512 per block, grid 1024 (4 blocks/CU ->
// 32 waves/CU target). Transposed mfma: lane's x-row = l15, reg quad = 4
// consecutive k (QK^T) / d (PV). Epilogue also writes out[:,0:D)=x.
// LDS: Q 32KB; after QK^T, bytes 0..16K alias P tile, 16K+ red arrays.
__global__ __launch_bounds__(512, 8) void k_attn(
    const float* __restrict__ x, const float* __restrict__ x_mask,
    const float* __restrict__ key_mask, const float* __restrict__ dot_w,
    const unsigned short* __restrict__ Kh, const unsigned short* __restrict__ KhT,
    const float* __restrict__ xlog, const float* __restrict__ klog,
    float* __restrict__ maxs, float* __restrict__ out) {
  __shared__ unsigned short Qall[16 * 1024];        // 32KB exactly
  unsigned short* Pt = Qall;                        // alias: 16KB P tile (PV phase)
  float* redA = (float*)(Qall + 8192);              // byte 16384+ (post-QK^T)
  float* redB = redA + 128;
  float* redC = redB + 128;

  const int tid = threadIdx.x;
  const int wv = tid >> 6;               // 0..7
  const int lane = tid & 63;
  const int l15 = lane & 15, l4 = lane >> 4;
  const int r7 = l15 & 7;

  int bid = blockIdx.x;
  int b = (bid & 7) * 2 + (bid >> 9);
  int x0 = ((bid >> 3) & 63) * 16;

  const unsigned short* KhB = Kh + (size_t)b * KL_ * D_;
  const float* xB = x + ((size_t)b * XL_ + x0) * D_;

  // ---- stage Q = fp16(x * dot_w), [16][1024], 16B-chunk XOR swizzle ----
  {
    int row = tid >> 5;                  // 0..15
    int cg = tid & 31;
    const float* sp = xB + (size_t)row * D_;
    char* qrow = (char*)Qall + row * 2048;
    int rsw = row & 7;
#pragma unroll
    for (int j = 0; j < 8; ++j) {
      int c4 = cg + j * 32;              // float4 index 0..255
      float4 v = *(const float4*)(sp + c4 * 4);
      float4 w = *(const float4*)(dot_w + c4 * 4);
      u16x4 hv;
      hv[0] = f2h(v.x * w.x); hv[1] = f2h(v.y * w.y);
      hv[2] = f2h(v.z * w.z); hv[3] = f2h(v.w * w.w);
      *(u16x4*)(qrow + (((c4 >> 1) ^ rsw) << 4) + ((c4 & 1) << 3)) = hv;
    }
  }
  __syncthreads();

  // ---- QK^T (transposed): acc[n] = mfma(Kfrag_n, Qfrag) ----
  // acc[n][q]: x-row = l15, k = wv*64 + n*16 + l4*4 + q
  f32x4 acc[4];
#pragma unroll
  for (int n = 0; n < 4; ++n) { f32x4 z = {0.f, 0.f, 0.f, 0.f}; acc[n] = z; }

  const unsigned short* bp[4];
#pragma unroll
  for (int n = 0; n < 4; ++n)
    bp[n] = KhB + (size_t)(wv * 64 + n * 16 + l15) * D_ + l4 * 8;
  const char* qa0 = (char*)Qall + l15 * 2048;

#pragma unroll 2
  for (int dk = 0; dk < D_; dk += 32) {
    f16x8 b0 = *(const f16x8*)(bp[0] + dk);
    f16x8 b1 = *(const f16x8*)(bp[1] + dk);
    f16x8 b2 = *(const f16x8*)(bp[2] + dk);
    f16x8 b3 = *(const f16x8*)(bp[3] + dk);
    int c = (((dk >> 3) + l4) ^ r7) << 4;
    f16x8 a0 = *(const f16x8*)(qa0 + c);
    __builtin_amdgcn_s_setprio(1);
    acc[0] = __builtin_amdgcn_mfma_f32_16x16x32_f16(b0, a0, acc[0], 0, 0, 0);
    acc[1] = __builtin_amdgcn_mfma_f32_16x16x32_f16(b1, a0, acc[1], 0, 0, 0);
    acc[2] = __builtin_amdgcn_mfma_f32_16x16x32_f16(b2, a0, acc[2], 0, 0, 0);
    acc[3] = __builtin_amdgcn_mfma_f32_16x16x32_f16(b3, a0, acc[3], 0, 0, 0);
    __builtin_amdgcn_s_setprio(0);
  }
  __syncthreads();   // Q region dead beyond this point

  // ---- softmax over KL ----
  int row = l15;
  float xlv = xlog[(size_t)b * XL_ + x0 + row];
  float xmv = x_mask[(size_t)b * XL_ + x0 + row];
  f32x4 klv[4], kmv[4];
#pragma unroll
  for (int n = 0; n < 4; ++n) {
    int kb = wv * 64 + n * 16 + l4 * 4;
    klv[n] = *(const f32x4*)(klog + (size_t)b * KL_ + kb);
    kmv[n] = *(const f32x4*)(key_mask + (size_t)b * KL_ + kb);
  }
  float mxsm = -3.0e38f, mxs2 = -3.0e38f;
#pragma unroll
  for (int n = 0; n < 4; ++n)
#pragma unroll
    for (int q = 0; q < 4; ++q) {
      float s = acc[n][q] + xlv + klv[n][q];
      float sm = s + (1.f - xmv * kmv[n][q]) * NEGC;
      float s2 = s * kmv[n][q] + (1.f - kmv[n][q]) * NEGC;
      mxsm = fmaxf(mxsm, sm);
      mxs2 = fmaxf(mxs2, s2);
    }
  mxsm = fmaxf(mxsm, __shfl_xor(mxsm, 16));
  mxsm = fmaxf(mxsm, __shfl_xor(mxsm, 32));
  mxs2 = fmaxf(mxs2, __shfl_xor(mxs2, 16));
  mxs2 = fmaxf(mxs2, __shfl_xor(mxs2, 32));
  if (l4 == 0) {
    redA[wv * 16 + row] = mxsm;
    redB[wv * 16 + row] = mxs2;
  }
  __syncthreads();
  float gmx;
  {
    float v = redA[row];
#pragma unroll
    for (int w = 1; w < 8; ++w) v = fmaxf(v, redA[w * 16 + row]);
    gmx = v;
  }
  if (tid < 16) {
    float v = redB[tid];
#pragma unroll
    for (int w = 1; w < 8; ++w) v = fmaxf(v, redB[w * 16 + tid]);
    maxs[(size_t)b * XL_ + x0 + tid] = v;
  }
  // exp pass: P^ written as [x-row][k] fp16, 8B granules, XOR-swizzled
  float rs = 0.f;
  {
    char* prow = (char*)Pt + row * 1024;
    int rsw = row & 7;
#pragma unroll
    for (int n = 0; n < 4; ++n) {
      int k = wv * 64 + n * 16 + l4 * 4;
      u16x4 pk;
#pragma unroll
      for (int q = 0; q < 4; ++q) {
        float s = acc[n][q] + xlv + klv[n][q];
        float sm = s + (1.f - xmv * kmv[n][q]) * NEGC;
        float e = __expf(sm - gmx);
        rs += e;
        pk[q] = f2h(e);
      }
      *(u16x4*)(prow + ((((k >> 3) ^ rsw) << 4) + ((k & 4) << 1))) = pk;
    }
  }
  rs += __shfl_xor(rs, 16);
  rs += __shfl_xor(rs, 32);
  if (l4 == 0) redC[wv * 16 + row] = rs;
  __syncthreads();

  // ---- PV (transposed): acc2[n] = mfma(KhTfrag_n, Pfrag) ----
  // acc2[n][q]: x-row = l15, d = c0 + n*16 + l4*4 + q
  float dn;
  {
    float sum = redC[row];
#pragma unroll
    for (int w = 1; w < 8; ++w) sum += redC[w * 16 + row];
    dn = 1.f / sum;
  }
  const unsigned short* KhTB = KhT + (size_t)b * D_ * KL_;
  size_t obase0 = ((size_t)b * XL_ + x0) * (size_t)(4 * D_);
  const char* pa0 = (char*)Pt + l15 * 1024;
#pragma unroll
  for (int sc = 0; sc < 2; ++sc) {
    int c0 = wv * 128 + sc * 64;
    f32x4 acc2[4];
#pragma unroll
    for (int n = 0; n < 4; ++n) { f32x4 z = {0.f, 0.f, 0.f, 0.f}; acc2[n] = z; }
    const unsigned short* tp[4];
#pragma unroll
    for (int n = 0; n < 4; ++n)
      tp[n] = KhTB + (size_t)(c0 + n * 16 + l15) * KL_ + l4 * 8;
#pragma unroll 2
    for (int kk = 0; kk < KL_; kk += 32) {
      f16x8 b0 = *(const f16x8*)(tp[0] + kk);
      f16x8 b1 = *(const f16x8*)(tp[1] + kk);
      f16x8 b2 = *(const f16x8*)(tp[2] + kk);
      f16x8 b3 = *(const f16x8*)(tp[3] + kk);
      int c = ((((kk >> 3) + l4) ^ r7) << 4);
      f16x8 a0 = *(const f16x8*)(pa0 + c);
      __builtin_amdgcn_s_setprio(1);
      acc2[0] = __builtin_amdgcn_mfma_f32_16x16x32_f16(b0, a0, acc2[0], 0, 0, 0);
      acc2[1] = __builtin_amdgcn_mfma_f32_16x16x32_f16(b1, a0, acc2[1], 0, 0, 0);
      acc2[2] = __builtin_amdgcn_mfma_f32_16x16x32_f16(b2, a0, acc2[2], 0, 0, 0);
      acc2[3] = __builtin_amdgcn_mfma_f32_16x16x32_f16(b3, a0, acc2[3], 0, 0, 0);
      __builtin_amdgcn_s_setprio(0);
    }
    {
      size_t ob = obase0 + (size_t)row * (4 * D_);
      const float* xr = xB + (size_t)row * D_;
#pragma unroll
      for (int n = 0; n < 4; ++n) {
        int col = c0 + n * 16 + l4 * 4;
        f32x4 v = acc2[n];
        v[0] *= dn; v[1] *= dn; v[2] *= dn; v[3] *= dn;
        f32x4 xv = *(const f32x4*)(xr + col);
        *(f32x4*)(out + ob + col) = xv;                 // out[:,0:D) = x
        *(f32x4*)(out + ob + D_ + col) = v;             // x2key
        f32x4 pv;
        pv[0] = v[0] * xv[0]; pv[1] = v[1] * xv[1];
        pv[2] = v[2] * xv[2]; pv[3] = v[3] * xv[3];
        *(f32x4*)(out + ob + 2 * D_ + col) = pv;        // x * x2key
      }
    }
  }
}

// ---------- p = normalized softmax(max_s * x_mask) * x_mask, per batch ----------
__global__ __launch_bounds__(256) void k_p(const float* __restrict__ maxs,
    const float* __restrict__ x_mask, float* __restrict__ pbuf) {
  int b = blockIdx.x, tid = threadIdx.x;
  int wv = tid >> 6, lane = tid & 63;
  __shared__ float r1[4], r2[4], r3[4];
  const float* ms = maxs + (size_t)b * XL_;
  const float* xm = x_mask + (size_t)b * XL_;
  float tv[4], xmv[4];
  float vmax = -3.0e38f;
#pragma unroll
  for (int i = 0; i < 4; ++i) {
    int xi = i * 256 + tid;
    xmv[i] = xm[xi];
    tv[i] = ms[xi] * xmv[i];
    vmax = fmaxf(vmax, tv[i]);
  }
#pragma unroll
  for (int sh = 32; sh >= 1; sh >>= 1) vmax = fmaxf(vmax, __shfl_xor(vmax, sh));
  if (lane == 0) r1[wv] = vmax;
  __syncthreads();
  float gmax = fmaxf(fmaxf(r1[0], r1[1]), fmaxf(r1[2], r1[3]));
  float e[4]; float es = 0.f;
#pragma unroll
  for (int i = 0; i < 4; ++i) { e[i] = __expf(tv[i] - gmax); es += e[i]; }
#pragma unroll
  for (int sh = 32; sh >= 1; sh >>= 1) es += __shfl_xor(es, sh);
  if (lane == 0) r2[wv] = es;
  __syncthreads();
  float gsum = r2[0] + r2[1] + r2[2] + r2[3];
  float pv[4]; float ps = 0.f;
#pragma unroll
  for (int i = 0; i < 4; ++i) { pv[i] = e[i] / gsum * xmv[i]; ps += pv[i]; }
#pragma unroll
  for (int sh = 32; sh >= 1; sh >>= 1) ps += __shfl_xor(ps, sh);
  if (lane == 0) r3[wv] = ps;
  __syncthreads();
  float gps = r3[0] + r3[1] + r3[2] + r3[3];
  float inv = 1.f / (gps + 1e-13f);
#pragma unroll
  for (int i = 0; i < 4; ++i) pbuf[(size_t)b * XL_ + i * 256 + tid] = pv[i] * inv;
}

// ---------- key2x partials: block (b, xc) sums 64 x-rows ----------
__global__ __launch_bounds__(256) void k_key2x_part(const float* __restrict__ x,
    const float* __restrict__ pbuf, float* __restrict__ partial) {
  int b = blockIdx.x >> 4;
  int xc = blockIdx.x & 15;
  __shared__ float ps[64];
  if (threadIdx.x < 64) ps[threadIdx.x] = pbuf[(size_t)b * XL_ + xc * 64 + threadIdx.x];
  __syncthreads();
  const float* xb = x + ((size_t)b * XL_ + xc * 64) * D_;
  float acc0 = 0.f, acc1 = 0.f, acc2 = 0.f, acc3 = 0.f;
  int d = threadIdx.x;
  for (int xi = 0; xi < 64; ++xi) {
    float pv = ps[xi];
    const float* rp = xb + (size_t)xi * D_;
    acc0 += pv * rp[d];
    acc1 += pv * rp[d + 256];
    acc2 += pv * rp[d + 512];
    acc3 += pv * rp[d + 768];
  }
  float* pp = partial + (size_t)blockIdx.x * D_;
  pp[d] = acc0; pp[d + 256] = acc1; pp[d + 512] = acc2; pp[d + 768] = acc3;
}

// ---------- key2x reduce: k2x[b][d] = sum_xc partial ----------
__global__ __launch_bounds__(256) void k_key2x_red(const float* __restrict__ partial,
    float* __restrict__ k2x) {
  int idx = blockIdx.x * 256 + threadIdx.x;
  int b = idx >> 10;
  float s = 0.f;
#pragma unroll
  for (int xc = 0; xc < 16; ++xc)
    s += partial[((size_t)b * 16 + xc) * D_ + (idx & 1023)];
  k2x[idx] = s;
}

// ---------- out[.,3D:4D) = x * key2x ----------
__global__ __launch_bounds__(256) void k_outfinal(const float* __restrict__ x,
    const float* __restrict__ k2x, float* __restrict__ out) {
  size_t t = (size_t)blockIdx.x * 256 + threadIdx.x;
  size_t base = t * 4;
  int b = (int)(base >> 20);
  int rem = (int)(base & ((1u << 20) - 1));
  int xr = rem >> 10;
  int d = rem & 1023;
  float4 xv = *(const float4*)(x + base);
  float4 kv = *(const float4*)(k2x + (size_t)b * D_ + d);
  float* orow = out + ((size_t)b * XL_ + xr) * (size_t)(4 * D_);
  float4 pr;
  pr.x = xv.x * kv.x; pr.y = xv.y * kv.y; pr.z = xv.z * kv.z; pr.w = xv.w * kv.w;
  *(float4*)(orow + 3 * D_ + d) = pr;
}

extern "C" void kernel_launch(void* const* d_in, const int* in_sizes, int n_in,
                              void* d_out, int out_size, void* d_ws, size_t ws_size,
                              hipStream_t stream) {
  (void)in_sizes; (void)n_in; (void)out_size; (void)ws_size;
  const float* x        = (const float*)d_in[0];
  const float* x_mask   = (const float*)d_in[1];
  const float* key      = (const float*)d_in[2];
  const float* key_mask = (const float*)d_in[3];
  const float* w_input  = (const float*)d_in[4];
  const float* w_key    = (const float*)d_in[5];
  const float* dot_w    = (const float*)d_in[6];
  float* out = (float*)d_out;
  char* ws = (char*)d_ws;

  unsigned short* Kh  = (unsigned short*)ws;                        // 16 MB
  unsigned short* KhT = (unsigned short*)(ws + (16u << 20));        // 16 MB
  float* xlog = (float*)(ws + (32u << 20));                         // 64 KB
  float* klog = xlog + B_ * XL_;                                    // 32 KB
  float* maxs = klog + B_ * KL_;                                    // 64 KB
  float* pbuf = maxs + B_ * XL_;                                    // 64 KB
  float* k2x  = pbuf + B_ * XL_;                                    // 64 KB
  float* partial = (float*)ws;   // 1 MB, aliases Kh (dead after k_attn)

  k_prep_key<<<dim3(B_ * KL_ / 4), dim3(256), 0, stream>>>(key, w_key, Kh, klog);
  k_prep_x<<<dim3(B_ * XL_ / 4), dim3(256), 0, stream>>>(x, w_input, xlog);
  k_transpose<<<dim3(B_ * 128), dim3(256), 0, stream>>>(Kh, KhT);
  k_attn<<<dim3(1024), dim3(512), 0, stream>>>(x, x_mask, key_mask, dot_w,
                                               Kh, KhT, xlog, klog, maxs, out);
  k_p<<<dim3(B_), dim3(256), 0, stream>>>(maxs, x_mask, pbuf);
  k_key2x_part<<<dim3(B_ * 16), dim3(256), 0, stream>>>(x, pbuf, partial);
  k_key2x_red<<<dim3(B_ * D_ / 256), dim3(256), 0, stream>>>(partial, k2x);
  k_outfinal<<<dim3(B_ * XL_ * D_ / 1024), dim3(256), 0, stream>>>(x, k2x, out);
}

// Round 5
// 181.309 us; speedup vs baseline: 1.8369x; 1.8369x over previous
//
#include <hip/hip_runtime.h>
#include <hip/hip_fp16.h>

#define B_ 16
#define XL_ 1024
#define KL_ 512
#define D_ 1024
#define NEGC (-10000000.0f)

typedef _Float16 f16x8 __attribute__((ext_vector_type(8)));
typedef float f32x4 __attribute__((ext_vector_type(4)));
typedef unsigned short u16x8 __attribute__((ext_vector_type(8)));
typedef unsigned short u16x4 __attribute__((ext_vector_type(4)));

__device__ __forceinline__ unsigned short f2h(float f) {
  __half h = __float2half(f);
  return __half_as_ushort(h);
}

// ---------- prep: x_logits = x . w_input (wave per row) ----------
__global__ __launch_bounds__(256) void k_prep_x(const float* __restrict__ x,
    const float* __restrict__ w_input, float* __restrict__ xlog) {
  int wv = threadIdx.x >> 6, lane = threadIdx.x & 63;
  int row = blockIdx.x * 4 + wv;
  const float* src = x + (size_t)row * D_;
  float acc = 0.f;
#pragma unroll
  for (int j = 0; j < 4; ++j) {
    int d = j * 256 + lane * 4;
    float4 v = *(const float4*)(src + d);
    float4 w = *(const float4*)(w_input + d);
    acc += v.x * w.x + v.y * w.y + v.z * w.z + v.w * w.w;
  }
#pragma unroll
  for (int sh = 32; sh >= 1; sh >>= 1) acc += __shfl_xor(acc, sh);
  if (lane == 0) xlog[row] = acc;
}

// ---------- build fragment-order K arrays + klog ----------
// KQ2[b][w8][dkc32][n4][lane64][8h]  : element (k,d), w=k>>6, n=(k>>4)&3,
//    l15=k&15, dkc=d>>5, l4=(d>>3)&3, h=d&7, lane=l4*16+l15
// KV2[b][w8][kkc16][n'8][lane64][8h] : element (d,k), w=d>>7, n'=(d>>4)&7,
//    l15=d&15, kkc=k>>5, l4=(k>>3)&3, h=k&7, lane=l4*16+l15
// One block per (b, kstrip of 64 rows); 256 thr.
__global__ __launch_bounds__(256) void k_build(const float* __restrict__ key,
    const float* __restrict__ w_key, unsigned short* __restrict__ KQ2,
    unsigned short* __restrict__ KV2, float* __restrict__ klog) {
  __shared__ unsigned short tile[64][72];
  int b = blockIdx.x >> 3, ks = blockIdx.x & 7;
  int tid = threadIdx.x;
  int kr = tid >> 2;          // local k-row 0..63
  int cq = tid & 3;           // col quarter
  const float* krow = key + ((size_t)(b * KL_ + ks * 64 + kr)) * D_;
  float klacc = 0.f;
  int dl = tid & 63, g = tid >> 6;

  for (int dt = 0; dt < 16; ++dt) {
    // stage 64x64 fp16 tile, accumulate klog partial
#pragma unroll
    for (int j = 0; j < 4; ++j) {
      int c = dt * 64 + cq * 16 + j * 4;
      float4 v = *(const float4*)(krow + c);
      float4 w = *(const float4*)(w_key + c);
      klacc += v.x * w.x + v.y * w.y + v.z * w.z + v.w * w.w;
      u16x4 hv;
      hv[0] = f2h(v.x); hv[1] = f2h(v.y); hv[2] = f2h(v.z); hv[3] = f2h(v.w);
      *(u16x4*)(&tile[kr][cq * 16 + j * 4]) = hv;
    }
    __syncthreads();
    // KQ2: thread (kr, cq=l4): for each of 2 dk-chunks write u16x8
#pragma unroll
    for (int dkc_l = 0; dkc_l < 2; ++dkc_l) {
      u16x8 hv = *(const u16x8*)(&tile[kr][dkc_l * 32 + cq * 8]);
      size_t dst = (((size_t)(b * 8 + ks) * 32 + (dt * 2 + dkc_l)) << 11)
                   + (size_t)(((kr >> 4) & 3) * 512 + (cq * 16 + (kr & 15)) * 8);
      *(u16x8*)(KQ2 + dst) = hv;
    }
    // KV2: thread (dl, g=l4): gather 8 k-halves per kk-chunk
    {
      int dglob = dt * 64 + dl;
      int wv_ = dglob >> 7, np = (dglob >> 4) & 7, l15v = dglob & 15;
#pragma unroll
      for (int kkc_l = 0; kkc_l < 2; ++kkc_l) {
        u16x8 hv;
#pragma unroll
        for (int h = 0; h < 8; ++h) hv[h] = tile[kkc_l * 32 + g * 8 + h][dl];
        size_t dst = (((size_t)(b * 8 + wv_) * 16 + (ks * 2 + kkc_l)) << 12)
                     + (size_t)(np * 512 + (g * 16 + l15v) * 8);
        *(u16x8*)(KV2 + dst) = hv;
      }
    }
    __syncthreads();
  }
  klacc += __shfl_xor(klacc, 1);
  klacc += __shfl_xor(klacc, 2);
  if (cq == 0) klog[b * KL_ + ks * 64 + kr] = klacc;
}

// ---------- main attention kernel ----------
// 512 thr (8 waves), 32 x-rows x KL=512 per block, 512 blocks.
// All K/KhT fragment loads are DENSE: fragment-order arrays, 64 lanes of one
// load read a contiguous 1KB run. MFMA math identical to R3 (transposed mfma:
// x-row = l15, k or d = l4*4+q via first operand).
__global__ __launch_bounds__(512, 4) void k_attn(
    const float* __restrict__ x, const float* __restrict__ x_mask,
    const float* __restrict__ key_mask, const float* __restrict__ dot_w,
    const unsigned short* __restrict__ KQ2, const unsigned short* __restrict__ KV2,
    const float* __restrict__ xlog, const float* __restrict__ klog,
    float* __restrict__ maxs, float* __restrict__ out) {
  __shared__ unsigned short Qall[32 * 1024];        // 64KB
  unsigned short* Pt = Qall;                        // alias: 32KB P tile
  float* redA = (float*)(Qall + 16384);             // byte 32768+
  float* redB = redA + 256;
  float* redC = redB + 256;

  const int tid = threadIdx.x;
  const int wv = tid >> 6;
  const int lane = tid & 63;
  const int l15 = lane & 15, l4 = lane >> 4;
  const int r7 = l15 & 7;

  int bid = blockIdx.x;
  int b = (bid & 7) * 2 + (bid >> 8);
  int x0 = ((bid >> 3) & 31) * 32;

  const float* xB = x + ((size_t)b * XL_ + x0) * D_;

  // ---- stage Q = fp16(x * dot_w), [32][1024], 16B-chunk XOR swizzle ----
  {
    int row = tid >> 4;
    int cg = tid & 15;
    const float* sp = xB + (size_t)row * D_;
    char* qrow = (char*)Qall + row * 2048;
    int rsw = row & 7;
#pragma unroll
    for (int j = 0; j < 16; ++j) {
      int c4 = cg + j * 16;
      float4 v = *(const float4*)(sp + c4 * 4);
      float4 w = *(const float4*)(dot_w + c4 * 4);
      u16x4 hv;
      hv[0] = f2h(v.x * w.x); hv[1] = f2h(v.y * w.y);
      hv[2] = f2h(v.z * w.z); hv[3] = f2h(v.w * w.w);
      *(u16x4*)(qrow + (((c4 >> 1) ^ rsw) << 4) + ((c4 & 1) << 3)) = hv;
    }
  }
  __syncthreads();

  // ---- QK^T: acc[m][n] = mfma(Kfrag_n, Qfrag_m) ----
  f32x4 acc[2][4];
#pragma unroll
  for (int m = 0; m < 2; ++m)
#pragma unroll
    for (int n = 0; n < 4; ++n) { f32x4 z = {0.f, 0.f, 0.f, 0.f}; acc[m][n] = z; }

  const unsigned short* KQ2w = KQ2 + (((size_t)(b * 8 + wv) * 32) << 11) + lane * 8;
  const char* qa0 = (char*)Qall + l15 * 2048;
  const char* qa1 = (char*)Qall + (16 + l15) * 2048;

#pragma unroll 2
  for (int dk = 0; dk < D_; dk += 32) {
    const unsigned short* cp = KQ2w + ((dk >> 5) << 11);
    f16x8 b0 = *(const f16x8*)(cp);
    f16x8 b1 = *(const f16x8*)(cp + 512);
    f16x8 b2 = *(const f16x8*)(cp + 1024);
    f16x8 b3 = *(const f16x8*)(cp + 1536);
    int c = (((dk >> 3) + l4) ^ r7) << 4;
    f16x8 a0 = *(const f16x8*)(qa0 + c);
    f16x8 a1 = *(const f16x8*)(qa1 + c);
    __builtin_amdgcn_s_setprio(1);
    acc[0][0] = __builtin_amdgcn_mfma_f32_16x16x32_f16(b0, a0, acc[0][0], 0, 0, 0);
    acc[1][0] = __builtin_amdgcn_mfma_f32_16x16x32_f16(b0, a1, acc[1][0], 0, 0, 0);
    acc[0][1] = __builtin_amdgcn_mfma_f32_16x16x32_f16(b1, a0, acc[0][1], 0, 0, 0);
    acc[1][1] = __builtin_amdgcn_mfma_f32_16x16x32_f16(b1, a1, acc[1][1], 0, 0, 0);
    acc[0][2] = __builtin_amdgcn_mfma_f32_16x16x32_f16(b2, a0, acc[0][2], 0, 0, 0);
    acc[1][2] = __builtin_amdgcn_mfma_f32_16x16x32_f16(b2, a1, acc[1][2], 0, 0, 0);
    acc[0][3] = __builtin_amdgcn_mfma_f32_16x16x32_f16(b3, a0, acc[0][3], 0, 0, 0);
    acc[1][3] = __builtin_amdgcn_mfma_f32_16x16x32_f16(b3, a1, acc[1][3], 0, 0, 0);
    __builtin_amdgcn_s_setprio(0);
  }
  __syncthreads();   // Q region dead beyond this point

  // ---- softmax over KL ----
  float xlv[2], xmv[2];
#pragma unroll
  for (int m = 0; m < 2; ++m) {
    int row = m * 16 + l15;
    xlv[m] = xlog[(size_t)b * XL_ + x0 + row];
    xmv[m] = x_mask[(size_t)b * XL_ + x0 + row];
  }
  f32x4 klv[4], kmv[4];
#pragma unroll
  for (int n = 0; n < 4; ++n) {
    int kb = wv * 64 + n * 16 + l4 * 4;
    klv[n] = *(const f32x4*)(klog + (size_t)b * KL_ + kb);
    kmv[n] = *(const f32x4*)(key_mask + (size_t)b * KL_ + kb);
  }
  float mxsm[2] = {-3.0e38f, -3.0e38f}, mxs2[2] = {-3.0e38f, -3.0e38f};
#pragma unroll
  for (int m = 0; m < 2; ++m)
#pragma unroll
    for (int n = 0; n < 4; ++n)
#pragma unroll
      for (int q = 0; q < 4; ++q) {
        float s = acc[m][n][q] + xlv[m] + klv[n][q];
        float sm = s + (1.f - xmv[m] * kmv[n][q]) * NEGC;
        float s2 = s * kmv[n][q] + (1.f - kmv[n][q]) * NEGC;
        mxsm[m] = fmaxf(mxsm[m], sm);
        mxs2[m] = fmaxf(mxs2[m], s2);
      }
#pragma unroll
  for (int m = 0; m < 2; ++m) {
    mxsm[m] = fmaxf(mxsm[m], __shfl_xor(mxsm[m], 16));
    mxsm[m] = fmaxf(mxsm[m], __shfl_xor(mxsm[m], 32));
    mxs2[m] = fmaxf(mxs2[m], __shfl_xor(mxs2[m], 16));
    mxs2[m] = fmaxf(mxs2[m], __shfl_xor(mxs2[m], 32));
  }
  if (l4 == 0) {
#pragma unroll
    for (int m = 0; m < 2; ++m) {
      redA[wv * 32 + m * 16 + l15] = mxsm[m];
      redB[wv * 32 + m * 16 + l15] = mxs2[m];
    }
  }
  __syncthreads();
  float gmx[2];
#pragma unroll
  for (int m = 0; m < 2; ++m) {
    int row = m * 16 + l15;
    float v = redA[row];
#pragma unroll
    for (int w = 1; w < 8; ++w) v = fmaxf(v, redA[w * 32 + row]);
    gmx[m] = v;
  }
  if (tid < 32) {
    float v = redB[tid];
#pragma unroll
    for (int w = 1; w < 8; ++w) v = fmaxf(v, redB[w * 32 + tid]);
    maxs[(size_t)b * XL_ + x0 + tid] = v;
  }
  // exp pass: P^ written as [x-row][k] fp16, 8B granules, XOR-swizzled
  float rs[2] = {0.f, 0.f};
#pragma unroll
  for (int m = 0; m < 2; ++m) {
    int row = m * 16 + l15;
    char* prow = (char*)Pt + row * 1024;
    int rsw = row & 7;
#pragma unroll
    for (int n = 0; n < 4; ++n) {
      int k = wv * 64 + n * 16 + l4 * 4;
      u16x4 pk;
#pragma unroll
      for (int q = 0; q < 4; ++q) {
        float s = acc[m][n][q] + xlv[m] + klv[n][q];
        float sm = s + (1.f - xmv[m] * kmv[n][q]) * NEGC;
        float e = __expf(sm - gmx[m]);
        rs[m] += e;
        pk[q] = f2h(e);
      }
      *(u16x4*)(prow + ((((k >> 3) ^ rsw) << 4) + ((k & 4) << 1))) = pk;
    }
  }
#pragma unroll
  for (int m = 0; m < 2; ++m) {
    rs[m] += __shfl_xor(rs[m], 16);
    rs[m] += __shfl_xor(rs[m], 32);
  }
  if (l4 == 0) {
#pragma unroll
    for (int m = 0; m < 2; ++m) redC[wv * 32 + m * 16 + l15] = rs[m];
  }
  __syncthreads();

  // ---- PV: acc2[m][n] = mfma(KhTfrag_n, Pfrag_m), dense KV2 loads ----
  float dn[2];
#pragma unroll
  for (int m = 0; m < 2; ++m) {
    int row = m * 16 + l15;
    float sum = redC[row];
#pragma unroll
    for (int w = 1; w < 8; ++w) sum += redC[w * 32 + row];
    dn[m] = 1.f / sum;
  }
  size_t obase0 = ((size_t)b * XL_ + x0) * (size_t)(4 * D_);
  const char* pa0 = (char*)Pt + l15 * 1024;
  const char* pa1 = (char*)Pt + (16 + l15) * 1024;
  const unsigned short* KV2w = KV2 + (((size_t)(b * 8 + wv) * 16) << 12) + lane * 8;
#pragma unroll
  for (int sc = 0; sc < 2; ++sc) {
    int c0 = wv * 128 + sc * 64;
    f32x4 acc2[2][4];
#pragma unroll
    for (int m = 0; m < 2; ++m)
#pragma unroll
      for (int n = 0; n < 4; ++n) { f32x4 z = {0.f, 0.f, 0.f, 0.f}; acc2[m][n] = z; }
    const unsigned short* KV2s = KV2w + sc * 4 * 512;
#pragma unroll 2
    for (int kk = 0; kk < KL_; kk += 32) {
      const unsigned short* cp = KV2s + ((kk >> 5) << 12);
      f16x8 b0 = *(const f16x8*)(cp);
      f16x8 b1 = *(const f16x8*)(cp + 512);
      f16x8 b2 = *(const f16x8*)(cp + 1024);
      f16x8 b3 = *(const f16x8*)(cp + 1536);
      int c = ((((kk >> 3) + l4) ^ r7) << 4);
      f16x8 a0 = *(const f16x8*)(pa0 + c);
      f16x8 a1 = *(const f16x8*)(pa1 + c);
      __builtin_amdgcn_s_setprio(1);
      acc2[0][0] = __builtin_amdgcn_mfma_f32_16x16x32_f16(b0, a0, acc2[0][0], 0, 0, 0);
      acc2[1][0] = __builtin_amdgcn_mfma_f32_16x16x32_f16(b0, a1, acc2[1][0], 0, 0, 0);
      acc2[0][1] = __builtin_amdgcn_mfma_f32_16x16x32_f16(b1, a0, acc2[0][1], 0, 0, 0);
      acc2[1][1] = __builtin_amdgcn_mfma_f32_16x16x32_f16(b1, a1, acc2[1][1], 0, 0, 0);
      acc2[0][2] = __builtin_amdgcn_mfma_f32_16x16x32_f16(b2, a0, acc2[0][2], 0, 0, 0);
      acc2[1][2] = __builtin_amdgcn_mfma_f32_16x16x32_f16(b2, a1, acc2[1][2], 0, 0, 0);
      acc2[0][3] = __builtin_amdgcn_mfma_f32_16x16x32_f16(b3, a0, acc2[0][3], 0, 0, 0);
      acc2[1][3] = __builtin_amdgcn_mfma_f32_16x16x32_f16(b3, a1, acc2[1][3], 0, 0, 0);
      __builtin_amdgcn_s_setprio(0);
    }
#pragma unroll
    for (int m = 0; m < 2; ++m) {
      int row = m * 16 + l15;
      size_t ob = obase0 + (size_t)row * (4 * D_);
      const float* xr = xB + (size_t)row * D_;
#pragma unroll
      for (int n = 0; n < 4; ++n) {
        int col = c0 + n * 16 + l4 * 4;
        f32x4 v = acc2[m][n];
        v[0] *= dn[m]; v[1] *= dn[m]; v[2] *= dn[m]; v[3] *= dn[m];
        f32x4 xv = *(const f32x4*)(xr + col);
        *(f32x4*)(out + ob + col) = xv;                 // out[:,0:D) = x
        *(f32x4*)(out + ob + D_ + col) = v;             // x2key
        f32x4 pv;
        pv[0] = v[0] * xv[0]; pv[1] = v[1] * xv[1];
        pv[2] = v[2] * xv[2]; pv[3] = v[3] * xv[3];
        *(f32x4*)(out + ob + 2 * D_ + col) = pv;        // x * x2key
      }
    }
  }
}

// ---------- p = normalized softmax(max_s * x_mask) * x_mask, per batch ----------
__global__ __launch_bounds__(256) void k_p(const float* __restrict__ maxs,
    const float* __restrict__ x_mask, float* __restrict__ pbuf) {
  int b = blockIdx.x, tid = threadIdx.x;
  int wv = tid >> 6, lane = tid & 63;
  __shared__ float r1[4], r2[4], r3[4];
  const float* ms = maxs + (size_t)b * XL_;
  const float* xm = x_mask + (size_t)b * XL_;
  float tv[4], xmv[4];
  float vmax = -3.0e38f;
#pragma unroll
  for (int i = 0; i < 4; ++i) {
    int xi = i * 256 + tid;
    xmv[i] = xm[xi];
    tv[i] = ms[xi] * xmv[i];
    vmax = fmaxf(vmax, tv[i]);
  }
#pragma unroll
  for (int sh = 32; sh >= 1; sh >>= 1) vmax = fmaxf(vmax, __shfl_xor(vmax, sh));
  if (lane == 0) r1[wv] = vmax;
  __syncthreads();
  float gmax = fmaxf(fmaxf(r1[0], r1[1]), fmaxf(r1[2], r1[3]));
  float e[4]; float es = 0.f;
#pragma unroll
  for (int i = 0; i < 4; ++i) { e[i] = __expf(tv[i] - gmax); es += e[i]; }
#pragma unroll
  for (int sh = 32; sh >= 1; sh >>= 1) es += __shfl_xor(es, sh);
  if (lane == 0) r2[wv] = es;
  __syncthreads();
  float gsum = r2[0] + r2[1] + r2[2] + r2[3];
  float pv[4]; float ps = 0.f;
#pragma unroll
  for (int i = 0; i < 4; ++i) { pv[i] = e[i] / gsum * xmv[i]; ps += pv[i]; }
#pragma unroll
  for (int sh = 32; sh >= 1; sh >>= 1) ps += __shfl_xor(ps, sh);
  if (lane == 0) r3[wv] = ps;
  __syncthreads();
  float gps = r3[0] + r3[1] + r3[2] + r3[3];
  float inv = 1.f / (gps + 1e-13f);
#pragma unroll
  for (int i = 0; i < 4; ++i) pbuf[(size_t)b * XL_ + i * 256 + tid] = pv[i] * inv;
}

// ---------- key2x partials: block (b, xc) sums 64 x-rows ----------
__global__ __launch_bounds__(256) void k_key2x_part(const float* __restrict__ x,
    const float* __restrict__ pbuf, float* __restrict__ partial) {
  int b = blockIdx.x >> 4;
  int xc = blockIdx.x & 15;
  __shared__ float ps[64];
  if (threadIdx.x < 64) ps[threadIdx.x] = pbuf[(size_t)b * XL_ + xc * 64 + threadIdx.x];
  __syncthreads();
  const float* xb = x + ((size_t)b * XL_ + xc * 64) * D_;
  float acc0 = 0.f, acc1 = 0.f, acc2 = 0.f, acc3 = 0.f;
  int d = threadIdx.x;
  for (int xi = 0; xi < 64; ++xi) {
    float pv = ps[xi];
    const float* rp = xb + (size_t)xi * D_;
    acc0 += pv * rp[d];
    acc1 += pv * rp[d + 256];
    acc2 += pv * rp[d + 512];
    acc3 += pv * rp[d + 768];
  }
  float* pp = partial + (size_t)blockIdx.x * D_;
  pp[d] = acc0; pp[d + 256] = acc1; pp[d + 512] = acc2; pp[d + 768] = acc3;
}

// ---------- key2x reduce: k2x[b][d] = sum_xc partial ----------
__global__ __launch_bounds__(256) void k_key2x_red(const float* __restrict__ partial,
    float* __restrict__ k2x) {
  int idx = blockIdx.x * 256 + threadIdx.x;
  int b = idx >> 10;
  float s = 0.f;
#pragma unroll
  for (int xc = 0; xc < 16; ++xc)
    s += partial[((size_t)b * 16 + xc) * D_ + (idx & 1023)];
  k2x[idx] = s;
}

// ---------- out[.,3D:4D) = x * key2x ----------
__global__ __launch_bounds__(256) void k_outfinal(const float* __restrict__ x,
    const float* __restrict__ k2x, float* __restrict__ out) {
  size_t t = (size_t)blockIdx.x * 256 + threadIdx.x;
  size_t base = t * 4;
  int b = (int)(base >> 20);
  int rem = (int)(base & ((1u << 20) - 1));
  int xr = rem >> 10;
  int d = rem & 1023;
  float4 xv = *(const float4*)(x + base);
  float4 kv = *(const float4*)(k2x + (size_t)b * D_ + d);
  float* orow = out + ((size_t)b * XL_ + xr) * (size_t)(4 * D_);
  float4 pr;
  pr.x = xv.x * kv.x; pr.y = xv.y * kv.y; pr.z = xv.z * kv.z; pr.w = xv.w * kv.w;
  *(float4*)(orow + 3 * D_ + d) = pr;
}

extern "C" void kernel_launch(void* const* d_in, const int* in_sizes, int n_in,
                              void* d_out, int out_size, void* d_ws, size_t ws_size,
                              hipStream_t stream) {
  (void)in_sizes; (void)n_in; (void)out_size; (void)ws_size;
  const float* x        = (const float*)d_in[0];
  const float* x_mask   = (const float*)d_in[1];
  const float* key      = (const float*)d_in[2];
  const float* key_mask = (const float*)d_in[3];
  const float* w_input  = (const float*)d_in[4];
  const float* w_key    = (const float*)d_in[5];
  const float* dot_w    = (const float*)d_in[6];
  float* out = (float*)d_out;
  char* ws = (char*)d_ws;

  unsigned short* KQ2 = (unsigned short*)ws;                        // 16 MB
  unsigned short* KV2 = (unsigned short*)(ws + (16u << 20));        // 16 MB
  float* xlog = (float*)(ws + (32u << 20));                         // 64 KB
  float* klog = xlog + B_ * XL_;                                    // 32 KB
  float* maxs = klog + B_ * KL_;                                    // 64 KB
  float* pbuf = maxs + B_ * XL_;                                    // 64 KB
  float* k2x  = pbuf + B_ * XL_;                                    // 64 KB
  float* partial = (float*)ws;   // 1 MB, aliases KQ2 (dead after k_attn)

  k_build<<<dim3(B_ * 8), dim3(256), 0, stream>>>(key, w_key, KQ2, KV2, klog);
  k_prep_x<<<dim3(B_ * XL_ / 4), dim3(256), 0, stream>>>(x, w_input, xlog);
  k_attn<<<dim3(512), dim3(512), 0, stream>>>(x, x_mask, key_mask, dot_w,
                                              KQ2, KV2, xlog, klog, maxs, out);
  k_p<<<dim3(B_), dim3(256), 0, stream>>>(maxs, x_mask, pbuf);
  k_key2x_part<<<dim3(B_ * 16), dim3(256), 0, stream>>>(x, pbuf, partial);
  k_key2x_red<<<dim3(B_ * D_ / 256), dim3(256), 0, stream>>>(partial, k2x);
  k_outfinal<<<dim3(B_ * XL_ * D_ / 1024), dim3(256), 0, stream>>>(x, k2x, out);
}

// Round 6
// 165.904 us; speedup vs baseline: 2.0074x; 1.0929x over previous
//
#include <hip/hip_runtime.h>
#include <hip/hip_fp16.h>

#define B_ 16
#define XL_ 1024
#define KL_ 512
#define D_ 1024
#define NEGC (-10000000.0f)

typedef _Float16 f16x8 __attribute__((ext_vector_type(8)));
typedef float f32x4 __attribute__((ext_vector_type(4)));
typedef unsigned short u16x8 __attribute__((ext_vector_type(8)));
typedef unsigned short u16x4 __attribute__((ext_vector_type(4)));

__device__ __forceinline__ unsigned short f2h(float f) {
  __half h = __float2half(f);
  return __half_as_ushort(h);
}

// ---------- build fragment-order K arrays + klog (atomic halves) ----------
// KQ2[b][w8][dkc32][n4][lane64][8h]  : element (k,d), w=k>>6, n=(k>>4)&3,
//    l15=k&15, dkc=d>>5, l4=(d>>3)&3, h=d&7, lane=l4*16+l15
// KV2[b][w8][kkc16][n'8][lane64][8h] : element (d,k), w=d>>7, n'=(d>>4)&7,
//    l15=d&15, kkc=k>>5, l4=(k>>3)&3, h=k&7, lane=l4*16+l15
// Block = (b, ks 64-row strip, dh 512-col half); 256 thr; 8 d-tiles each.
__global__ __launch_bounds__(256) void k_build(const float* __restrict__ key,
    const float* __restrict__ w_key, unsigned short* __restrict__ KQ2,
    unsigned short* __restrict__ KV2, float* __restrict__ klog) {
  __shared__ unsigned short tile[64][72];
  int bid = blockIdx.x;
  int b = bid >> 4;
  int ks = (bid >> 1) & 7;
  int dh = bid & 1;
  int tid = threadIdx.x;
  int kr = tid >> 2;          // local k-row 0..63
  int cq = tid & 3;           // col quarter
  const float* krow = key + ((size_t)(b * KL_ + ks * 64 + kr)) * D_;
  float klacc = 0.f;
  int dl = tid & 63, g = tid >> 6;

  for (int dt = dh * 8; dt < dh * 8 + 8; ++dt) {
#pragma unroll
    for (int j = 0; j < 4; ++j) {
      int c = dt * 64 + cq * 16 + j * 4;
      float4 v = *(const float4*)(krow + c);
      float4 w = *(const float4*)(w_key + c);
      klacc += v.x * w.x + v.y * w.y + v.z * w.z + v.w * w.w;
      u16x4 hv;
      hv[0] = f2h(v.x); hv[1] = f2h(v.y); hv[2] = f2h(v.z); hv[3] = f2h(v.w);
      *(u16x4*)(&tile[kr][cq * 16 + j * 4]) = hv;
    }
    __syncthreads();
    // KQ2: thread (kr, cq=l4): for each of 2 dk-chunks write u16x8
#pragma unroll
    for (int dkc_l = 0; dkc_l < 2; ++dkc_l) {
      u16x8 hv = *(const u16x8*)(&tile[kr][dkc_l * 32 + cq * 8]);
      size_t dst = (((size_t)(b * 8 + ks) * 32 + (dt * 2 + dkc_l)) << 11)
                   + (size_t)(((kr >> 4) & 3) * 512 + (cq * 16 + (kr & 15)) * 8);
      *(u16x8*)(KQ2 + dst) = hv;
    }
    // KV2: thread (dl, g=l4): gather 8 k-halves per kk-chunk
    {
      int dglob = dt * 64 + dl;
      int wv_ = dglob >> 7, np = (dglob >> 4) & 7, l15v = dglob & 15;
#pragma unroll
      for (int kkc_l = 0; kkc_l < 2; ++kkc_l) {
        u16x8 hv;
#pragma unroll
        for (int h = 0; h < 8; ++h) hv[h] = tile[kkc_l * 32 + g * 8 + h][dl];
        size_t dst = (((size_t)(b * 8 + wv_) * 16 + (ks * 2 + kkc_l)) << 12)
                     + (size_t)(np * 512 + (g * 16 + l15v) * 8);
        *(u16x8*)(KV2 + dst) = hv;
      }
    }
    __syncthreads();
  }
  klacc += __shfl_xor(klacc, 1);
  klacc += __shfl_xor(klacc, 2);
  if (cq == 0) atomicAdd(&klog[b * KL_ + ks * 64 + kr], klacc);
}

// ---------- main attention kernel ----------
// 512 thr (8 waves), 32 x-rows x KL=512 per block, 512 blocks.
// Dense fragment-order K loads; x_logits fused into Q staging.
__global__ __launch_bounds__(512, 4) void k_attn(
    const float* __restrict__ x, const float* __restrict__ x_mask,
    const float* __restrict__ key_mask, const float* __restrict__ dot_w,
    const float* __restrict__ w_input,
    const unsigned short* __restrict__ KQ2, const unsigned short* __restrict__ KV2,
    const float* __restrict__ klog,
    float* __restrict__ maxs, float* __restrict__ out) {
  __shared__ unsigned short Qall[32 * 1024];        // 64KB
  __shared__ float xlg[32];                         // fused x_logits
  unsigned short* Pt = Qall;                        // alias: 32KB P tile
  float* redA = (float*)(Qall + 16384);             // byte 32768+
  float* redB = redA + 256;
  float* redC = redB + 256;

  const int tid = threadIdx.x;
  const int wv = tid >> 6;
  const int lane = tid & 63;
  const int l15 = lane & 15, l4 = lane >> 4;
  const int r7 = l15 & 7;

  int bid = blockIdx.x;
  int b = (bid & 7) * 2 + (bid >> 8);
  int x0 = ((bid >> 3) & 31) * 32;

  const float* xB = x + ((size_t)b * XL_ + x0) * D_;

  // ---- stage Q = fp16(x * dot_w), [32][1024], 16B-chunk XOR swizzle;
  //      accumulate x_logits = x . w_input on the fly ----
  {
    int row = tid >> 4;
    int cg = tid & 15;
    const float* sp = xB + (size_t)row * D_;
    char* qrow = (char*)Qall + row * 2048;
    int rsw = row & 7;
    float xl = 0.f;
#pragma unroll
    for (int j = 0; j < 16; ++j) {
      int c4 = cg + j * 16;
      float4 v = *(const float4*)(sp + c4 * 4);
      float4 w = *(const float4*)(dot_w + c4 * 4);
      float4 wi = *(const float4*)(w_input + c4 * 4);
      xl += v.x * wi.x + v.y * wi.y + v.z * wi.z + v.w * wi.w;
      u16x4 hv;
      hv[0] = f2h(v.x * w.x); hv[1] = f2h(v.y * w.y);
      hv[2] = f2h(v.z * w.z); hv[3] = f2h(v.w * w.w);
      *(u16x4*)(qrow + (((c4 >> 1) ^ rsw) << 4) + ((c4 & 1) << 3)) = hv;
    }
    xl += __shfl_xor(xl, 1);
    xl += __shfl_xor(xl, 2);
    xl += __shfl_xor(xl, 4);
    xl += __shfl_xor(xl, 8);
    if (cg == 0) xlg[row] = xl;
  }
  __syncthreads();

  // ---- QK^T: acc[m][n] = mfma(Kfrag_n, Qfrag_m), dense KQ2 loads ----
  f32x4 acc[2][4];
#pragma unroll
  for (int m = 0; m < 2; ++m)
#pragma unroll
    for (int n = 0; n < 4; ++n) { f32x4 z = {0.f, 0.f, 0.f, 0.f}; acc[m][n] = z; }

  const unsigned short* KQ2w = KQ2 + (((size_t)(b * 8 + wv) * 32) << 11) + lane * 8;
  const char* qa0 = (char*)Qall + l15 * 2048;
  const char* qa1 = (char*)Qall + (16 + l15) * 2048;

#pragma unroll 4
  for (int dk = 0; dk < D_; dk += 32) {
    const unsigned short* cp = KQ2w + ((dk >> 5) << 11);
    f16x8 b0 = *(const f16x8*)(cp);
    f16x8 b1 = *(const f16x8*)(cp + 512);
    f16x8 b2 = *(const f16x8*)(cp + 1024);
    f16x8 b3 = *(const f16x8*)(cp + 1536);
    int c = (((dk >> 3) + l4) ^ r7) << 4;
    f16x8 a0 = *(const f16x8*)(qa0 + c);
    f16x8 a1 = *(const f16x8*)(qa1 + c);
    __builtin_amdgcn_s_setprio(1);
    acc[0][0] = __builtin_amdgcn_mfma_f32_16x16x32_f16(b0, a0, acc[0][0], 0, 0, 0);
    acc[1][0] = __builtin_amdgcn_mfma_f32_16x16x32_f16(b0, a1, acc[1][0], 0, 0, 0);
    acc[0][1] = __builtin_amdgcn_mfma_f32_16x16x32_f16(b1, a0, acc[0][1], 0, 0, 0);
    acc[1][1] = __builtin_amdgcn_mfma_f32_16x16x32_f16(b1, a1, acc[1][1], 0, 0, 0);
    acc[0][2] = __builtin_amdgcn_mfma_f32_16x16x32_f16(b2, a0, acc[0][2], 0, 0, 0);
    acc[1][2] = __builtin_amdgcn_mfma_f32_16x16x32_f16(b2, a1, acc[1][2], 0, 0, 0);
    acc[0][3] = __builtin_amdgcn_mfma_f32_16x16x32_f16(b3, a0, acc[0][3], 0, 0, 0);
    acc[1][3] = __builtin_amdgcn_mfma_f32_16x16x32_f16(b3, a1, acc[1][3], 0, 0, 0);
    __builtin_amdgcn_s_setprio(0);
  }
  __syncthreads();   // Q region dead beyond this point

  // ---- softmax over KL ----
  float xlv[2], xmv[2];
#pragma unroll
  for (int m = 0; m < 2; ++m) {
    int row = m * 16 + l15;
    xlv[m] = xlg[row];
    xmv[m] = x_mask[(size_t)b * XL_ + x0 + row];
  }
  f32x4 klv[4], kmv[4];
#pragma unroll
  for (int n = 0; n < 4; ++n) {
    int kb = wv * 64 + n * 16 + l4 * 4;
    klv[n] = *(const f32x4*)(klog + (size_t)b * KL_ + kb);
    kmv[n] = *(const f32x4*)(key_mask + (size_t)b * KL_ + kb);
  }
  float mxsm[2] = {-3.0e38f, -3.0e38f}, mxs2[2] = {-3.0e38f, -3.0e38f};
#pragma unroll
  for (int m = 0; m < 2; ++m)
#pragma unroll
    for (int n = 0; n < 4; ++n)
#pragma unroll
      for (int q = 0; q < 4; ++q) {
        float s = acc[m][n][q] + xlv[m] + klv[n][q];
        float sm = s + (1.f - xmv[m] * kmv[n][q]) * NEGC;
        float s2 = s * kmv[n][q] + (1.f - kmv[n][q]) * NEGC;
        mxsm[m] = fmaxf(mxsm[m], sm);
        mxs2[m] = fmaxf(mxs2[m], s2);
      }
#pragma unroll
  for (int m = 0; m < 2; ++m) {
    mxsm[m] = fmaxf(mxsm[m], __shfl_xor(mxsm[m], 16));
    mxsm[m] = fmaxf(mxsm[m], __shfl_xor(mxsm[m], 32));
    mxs2[m] = fmaxf(mxs2[m], __shfl_xor(mxs2[m], 16));
    mxs2[m] = fmaxf(mxs2[m], __shfl_xor(mxs2[m], 32));
  }
  if (l4 == 0) {
#pragma unroll
    for (int m = 0; m < 2; ++m) {
      redA[wv * 32 + m * 16 + l15] = mxsm[m];
      redB[wv * 32 + m * 16 + l15] = mxs2[m];
    }
  }
  __syncthreads();
  float gmx[2];
#pragma unroll
  for (int m = 0; m < 2; ++m) {
    int row = m * 16 + l15;
    float v = redA[row];
#pragma unroll
    for (int w = 1; w < 8; ++w) v = fmaxf(v, redA[w * 32 + row]);
    gmx[m] = v;
  }
  if (tid < 32) {
    float v = redB[tid];
#pragma unroll
    for (int w = 1; w < 8; ++w) v = fmaxf(v, redB[w * 32 + tid]);
    maxs[(size_t)b * XL_ + x0 + tid] = v;
  }
  // exp pass: P^ written as [x-row][k] fp16, 8B granules, XOR-swizzled
  float rs[2] = {0.f, 0.f};
#pragma unroll
  for (int m = 0; m < 2; ++m) {
    int row = m * 16 + l15;
    char* prow = (char*)Pt + row * 1024;
    int rsw = row & 7;
#pragma unroll
    for (int n = 0; n < 4; ++n) {
      int k = wv * 64 + n * 16 + l4 * 4;
      u16x4 pk;
#pragma unroll
      for (int q = 0; q < 4; ++q) {
        float s = acc[m][n][q] + xlv[m] + klv[n][q];
        float sm = s + (1.f - xmv[m] * kmv[n][q]) * NEGC;
        float e = __expf(sm - gmx[m]);
        rs[m] += e;
        pk[q] = f2h(e);
      }
      *(u16x4*)(prow + ((((k >> 3) ^ rsw) << 4) + ((k & 4) << 1))) = pk;
    }
  }
#pragma unroll
  for (int m = 0; m < 2; ++m) {
    rs[m] += __shfl_xor(rs[m], 16);
    rs[m] += __shfl_xor(rs[m], 32);
  }
  if (l4 == 0) {
#pragma unroll
    for (int m = 0; m < 2; ++m) redC[wv * 32 + m * 16 + l15] = rs[m];
  }
  __syncthreads();

  // ---- PV: acc2[m][n] = mfma(KhTfrag_n, Pfrag_m), dense KV2 loads ----
  float dn[2];
#pragma unroll
  for (int m = 0; m < 2; ++m) {
    int row = m * 16 + l15;
    float sum = redC[row];
#pragma unroll
    for (int w = 1; w < 8; ++w) sum += redC[w * 32 + row];
    dn[m] = 1.f / sum;
  }
  size_t obase0 = ((size_t)b * XL_ + x0) * (size_t)(4 * D_);
  const char* pa0 = (char*)Pt + l15 * 1024;
  const char* pa1 = (char*)Pt + (16 + l15) * 1024;
  const unsigned short* KV2w = KV2 + (((size_t)(b * 8 + wv) * 16) << 12) + lane * 8;
#pragma unroll
  for (int sc = 0; sc < 2; ++sc) {
    int c0 = wv * 128 + sc * 64;
    f32x4 acc2[2][4];
#pragma unroll
    for (int m = 0; m < 2; ++m)
#pragma unroll
      for (int n = 0; n < 4; ++n) { f32x4 z = {0.f, 0.f, 0.f, 0.f}; acc2[m][n] = z; }
    const unsigned short* KV2s = KV2w + sc * 4 * 512;
#pragma unroll 4
    for (int kk = 0; kk < KL_; kk += 32) {
      const unsigned short* cp = KV2s + ((kk >> 5) << 12);
      f16x8 b0 = *(const f16x8*)(cp);
      f16x8 b1 = *(const f16x8*)(cp + 512);
      f16x8 b2 = *(const f16x8*)(cp + 1024);
      f16x8 b3 = *(const f16x8*)(cp + 1536);
      int c = ((((kk >> 3) + l4) ^ r7) << 4);
      f16x8 a0 = *(const f16x8*)(pa0 + c);
      f16x8 a1 = *(const f16x8*)(pa1 + c);
      __builtin_amdgcn_s_setprio(1);
      acc2[0][0] = __builtin_amdgcn_mfma_f32_16x16x32_f16(b0, a0, acc2[0][0], 0, 0, 0);
      acc2[1][0] = __builtin_amdgcn_mfma_f32_16x16x32_f16(b0, a1, acc2[1][0], 0, 0, 0);
      acc2[0][1] = __builtin_amdgcn_mfma_f32_16x16x32_f16(b1, a0, acc2[0][1], 0, 0, 0);
      acc2[1][1] = __builtin_amdgcn_mfma_f32_16x16x32_f16(b1, a1, acc2[1][1], 0, 0, 0);
      acc2[0][2] = __builtin_amdgcn_mfma_f32_16x16x32_f16(b2, a0, acc2[0][2], 0, 0, 0);
      acc2[1][2] = __builtin_amdgcn_mfma_f32_16x16x32_f16(b2, a1, acc2[1][2], 0, 0, 0);
      acc2[0][3] = __builtin_amdgcn_mfma_f32_16x16x32_f16(b3, a0, acc2[0][3], 0, 0, 0);
      acc2[1][3] = __builtin_amdgcn_mfma_f32_16x16x32_f16(b3, a1, acc2[1][3], 0, 0, 0);
      __builtin_amdgcn_s_setprio(0);
    }
#pragma unroll
    for (int m = 0; m < 2; ++m) {
      int row = m * 16 + l15;
      size_t ob = obase0 + (size_t)row * (4 * D_);
      const float* xr = xB + (size_t)row * D_;
#pragma unroll
      for (int n = 0; n < 4; ++n) {
        int col = c0 + n * 16 + l4 * 4;
        f32x4 v = acc2[m][n];
        v[0] *= dn[m]; v[1] *= dn[m]; v[2] *= dn[m]; v[3] *= dn[m];
        f32x4 xv = *(const f32x4*)(xr + col);
        *(f32x4*)(out + ob + col) = xv;                 // out[:,0:D) = x
        *(f32x4*)(out + ob + D_ + col) = v;             // x2key
        f32x4 pv;
        pv[0] = v[0] * xv[0]; pv[1] = v[1] * xv[1];
        pv[2] = v[2] * xv[2]; pv[3] = v[3] * xv[3];
        *(f32x4*)(out + ob + 2 * D_ + col) = pv;        // x * x2key
      }
    }
  }
}

// ---------- p = normalized softmax(max_s * x_mask) * x_mask, per batch ----------
__global__ __launch_bounds__(256) void k_p(const float* __restrict__ maxs,
    const float* __restrict__ x_mask, float* __restrict__ pbuf) {
  int b = blockIdx.x, tid = threadIdx.x;
  int wv = tid >> 6, lane = tid & 63;
  __shared__ float r1[4], r2[4], r3[4];
  const float* ms = maxs + (size_t)b * XL_;
  const float* xm = x_mask + (size_t)b * XL_;
  float tv[4], xmv[4];
  float vmax = -3.0e38f;
#pragma unroll
  for (int i = 0; i < 4; ++i) {
    int xi = i * 256 + tid;
    xmv[i] = xm[xi];
    tv[i] = ms[xi] * xmv[i];
    vmax = fmaxf(vmax, tv[i]);
  }
#pragma unroll
  for (int sh = 32; sh >= 1; sh >>= 1) vmax = fmaxf(vmax, __shfl_xor(vmax, sh));
  if (lane == 0) r1[wv] = vmax;
  __syncthreads();
  float gmax = fmaxf(fmaxf(r1[0], r1[1]), fmaxf(r1[2], r1[3]));
  float e[4]; float es = 0.f;
#pragma unroll
  for (int i = 0; i < 4; ++i) { e[i] = __expf(tv[i] - gmax); es += e[i]; }
#pragma unroll
  for (int sh = 32; sh >= 1; sh >>= 1) es += __shfl_xor(es, sh);
  if (lane == 0) r2[wv] = es;
  __syncthreads();
  float gsum = r2[0] + r2[1] + r2[2] + r2[3];
  float pv[4]; float ps = 0.f;
#pragma unroll
  for (int i = 0; i < 4; ++i) { pv[i] = e[i] / gsum * xmv[i]; ps += pv[i]; }
#pragma unroll
  for (int sh = 32; sh >= 1; sh >>= 1) ps += __shfl_xor(ps, sh);
  if (lane == 0) r3[wv] = ps;
  __syncthreads();
  float gps = r3[0] + r3[1] + r3[2] + r3[3];
  float inv = 1.f / (gps + 1e-13f);
#pragma unroll
  for (int i = 0; i < 4; ++i) pbuf[(size_t)b * XL_ + i * 256 + tid] = pv[i] * inv;
}

// ---------- key2x partials: block (b, xc) sums 64 x-rows ----------
__global__ __launch_bounds__(256) void k_key2x_part(const float* __restrict__ x,
    const float* __restrict__ pbuf, float* __restrict__ partial) {
  int b = blockIdx.x >> 4;
  int xc = blockIdx.x & 15;
  __shared__ float ps[64];
  if (threadIdx.x < 64) ps[threadIdx.x] = pbuf[(size_t)b * XL_ + xc * 64 + threadIdx.x];
  __syncthreads();
  const float* xb = x + ((size_t)b * XL_ + xc * 64) * D_;
  float acc0 = 0.f, acc1 = 0.f, acc2 = 0.f, acc3 = 0.f;
  int d = threadIdx.x;
  for (int xi = 0; xi < 64; ++xi) {
    float pv = ps[xi];
    const float* rp = xb + (size_t)xi * D_;
    acc0 += pv * rp[d];
    acc1 += pv * rp[d + 256];
    acc2 += pv * rp[d + 512];
    acc3 += pv * rp[d + 768];
  }
  float* pp = partial + (size_t)blockIdx.x * D_;
  pp[d] = acc0; pp[d + 256] = acc1; pp[d + 512] = acc2; pp[d + 768] = acc3;
}

// ---------- key2x reduce: k2x[b][d] = sum_xc partial ----------
__global__ __launch_bounds__(256) void k_key2x_red(const float* __restrict__ partial,
    float* __restrict__ k2x) {
  int idx = blockIdx.x * 256 + threadIdx.x;
  int b = idx >> 10;
  float s = 0.f;
#pragma unroll
  for (int xc = 0; xc < 16; ++xc)
    s += partial[((size_t)b * 16 + xc) * D_ + (idx & 1023)];
  k2x[idx] = s;
}

// ---------- out[.,3D:4D) = x * key2x ----------
__global__ __launch_bounds__(256) void k_outfinal(const float* __restrict__ x,
    const float* __restrict__ k2x, float* __restrict__ out) {
  size_t t = (size_t)blockIdx.x * 256 + threadIdx.x;
  size_t base = t * 4;
  int b = (int)(base >> 20);
  int rem = (int)(base & ((1u << 20) - 1));
  int xr = rem >> 10;
  int d = rem & 1023;
  float4 xv = *(const float4*)(x + base);
  float4 kv = *(const float4*)(k2x + (size_t)b * D_ + d);
  float* orow = out + ((size_t)b * XL_ + xr) * (size_t)(4 * D_);
  float4 pr;
  pr.x = xv.x * kv.x; pr.y = xv.y * kv.y; pr.z = xv.z * kv.z; pr.w = xv.w * kv.w;
  *(float4*)(orow + 3 * D_ + d) = pr;
}

extern "C" void kernel_launch(void* const* d_in, const int* in_sizes, int n_in,
                              void* d_out, int out_size, void* d_ws, size_t ws_size,
                              hipStream_t stream) {
  (void)in_sizes; (void)n_in; (void)out_size; (void)ws_size;
  const float* x        = (const float*)d_in[0];
  const float* x_mask   = (const float*)d_in[1];
  const float* key      = (const float*)d_in[2];
  const float* key_mask = (const float*)d_in[3];
  const float* w_input  = (const float*)d_in[4];
  const float* w_key    = (const float*)d_in[5];
  const float* dot_w    = (const float*)d_in[6];
  float* out = (float*)d_out;
  char* ws = (char*)d_ws;

  unsigned short* KQ2 = (unsigned short*)ws;                        // 16 MB
  unsigned short* KV2 = (unsigned short*)(ws + (16u << 20));        // 16 MB
  float* xlog = (float*)(ws + (32u << 20));                         // 64 KB (unused)
  float* klog = xlog + B_ * XL_;                                    // 32 KB
  float* maxs = klog + B_ * KL_;                                    // 64 KB
  float* pbuf = maxs + B_ * XL_;                                    // 64 KB
  float* k2x  = pbuf + B_ * XL_;                                    // 64 KB
  float* partial = (float*)ws;   // 1 MB, aliases KQ2 (dead after k_attn)

  hipMemsetAsync(klog, 0, B_ * KL_ * sizeof(float), stream);
  k_build<<<dim3(B_ * 16), dim3(256), 0, stream>>>(key, w_key, KQ2, KV2, klog);
  k_attn<<<dim3(512), dim3(512), 0, stream>>>(x, x_mask, key_mask, dot_w, w_input,
                                              KQ2, KV2, klog, maxs, out);
  k_p<<<dim3(B_), dim3(256), 0, stream>>>(maxs, x_mask, pbuf);
  k_key2x_part<<<dim3(B_ * 16), dim3(256), 0, stream>>>(x, pbuf, partial);
  k_key2x_red<<<dim3(B_ * D_ / 256), dim3(256), 0, stream>>>(partial, k2x);
  k_outfinal<<<dim3(B_ * XL_ * D_ / 1024), dim3(256), 0, stream>>>(x, k2x, out);
}